// Round 2
// baseline (1516.197 us; speedup 1.0000x reference)
//
#include <hip/hip_runtime.h>

// Chunked VMM with per-128-K-chunk ADC quantization.
//   out[b,n] = sum_{c} q( sum_{k in chunk c} x[b,k]*w[n,k] ) + bias[n]
//   q(p) = round(clip(p,+-2.56) * 255/2.56) * 2.56/255   (round = RTNE)
// Strategy: cast x -> bf16, cast w -> bf16 PRE-SCALED by s=255/2.56 so GEMM
// partials are directly in ADC units; per chunk: med3 clamp, v_rndne, add to
// master accumulator. Final: out = master * (2.56/255) + bias.
// GEMM: 128x128 tile, BK=64, 4 waves x 64x64 (4x4 of mfma_f32_16x16x32_bf16),
// global_load_lds width=16.
// R2: XOR-swizzled LDS chunk layout (physical chunk = logical ^ (row&7)) to
// kill the 16-way bank conflicts seen in R1 (SQ_LDS_BANK_CONFLICT=1.0e8);
// launch_bounds(256,4) for 4 blocks/CU; grid-stride vectorized casts.

typedef __attribute__((ext_vector_type(8))) short short8;    // 8 bf16 = 4 VGPRs
typedef __attribute__((ext_vector_type(4))) float floatx4;   // MFMA C/D

#define BM 128
#define BN 128
#define BK 64

static __device__ __forceinline__ unsigned short f2bf(float f) {
    union { float f; unsigned int u; } v; v.f = f;
    unsigned int u = v.u;
    unsigned int r = (u + 0x7fffu + ((u >> 16) & 1u)) >> 16;  // RTNE
    return (unsigned short)r;
}

__global__ void cast_x_kernel(const float* __restrict__ in,
                              unsigned short* __restrict__ out, long n4) {
    const long stride = (long)gridDim.x * 256 * 4;
    for (long base = ((long)blockIdx.x * 256 + threadIdx.x) * 4; base < n4; base += stride) {
        #pragma unroll
        for (int j = 0; j < 4; ++j) {
            long i = base + j;
            if (i < n4) {
                float4 v = ((const float4*)in)[i];
                ushort4 o;
                o.x = f2bf(v.x); o.y = f2bf(v.y); o.z = f2bf(v.z); o.w = f2bf(v.w);
                ((ushort4*)out)[i] = o;
            }
        }
    }
}

__global__ void cast_w_kernel(const float* __restrict__ in,
                              unsigned short* __restrict__ out, long n4) {
    const float s = 99.609375f;  // 255/2.56 exact
    const long stride = (long)gridDim.x * 256 * 4;
    for (long base = ((long)blockIdx.x * 256 + threadIdx.x) * 4; base < n4; base += stride) {
        #pragma unroll
        for (int j = 0; j < 4; ++j) {
            long i = base + j;
            if (i < n4) {
                float4 v = ((const float4*)in)[i];
                ushort4 o;
                o.x = f2bf(v.x * s); o.y = f2bf(v.y * s);
                o.z = f2bf(v.z * s); o.w = f2bf(v.w * s);
                ((ushort4*)out)[i] = o;
            }
        }
    }
}

__global__ __launch_bounds__(256, 4) void vmm_kernel(
    const unsigned short* __restrict__ A,   // x   [B,K] bf16
    const unsigned short* __restrict__ Bw,  // w*s [N,K] bf16 (K-contiguous: B^T gemm)
    const float* __restrict__ bias,
    float* __restrict__ out,
    int N, int K)
{
    __shared__ unsigned short sA[BM * BK];
    __shared__ unsigned short sB[BN * BK];

    const int tid  = threadIdx.x;
    const int wid  = tid >> 6;
    const int lane = tid & 63;

    const int m0 = blockIdx.y * BM;
    const int n0 = blockIdx.x * BN;

    const int waveM = (wid >> 1) * 64;
    const int waveN = (wid & 1) * 64;

    floatx4 acc[4][4];   // partial (ADC units), reset every 128 K
    floatx4 macc[4][4];  // master accumulator
    #pragma unroll
    for (int i = 0; i < 4; ++i)
        #pragma unroll
        for (int j = 0; j < 4; ++j) {
            acc[i][j]  = (floatx4){0.f, 0.f, 0.f, 0.f};
            macc[i][j] = (floatx4){0.f, 0.f, 0.f, 0.f};
        }

    // staging: 16 segments of 1 KiB (8 rows x 8 chunks of 16B); 8 lanes/row.
    // XOR swizzle: physical chunk pc holds logical chunk pc ^ (row&7), so the
    // lane at physical (srow, pc) must FETCH global chunk pc ^ srow.
    const int srow = lane >> 3;                        // row within segment 0..7
    const int scol = (((lane & 7) ^ srow) & 7) * 8;    // swizzled bf16 col offset

    const unsigned short* gA = A  + (long)m0 * K;
    const unsigned short* gB = Bw + (long)n0 * K;

    for (int k0 = 0; k0 < K; k0 += BK) {
        #pragma unroll
        for (int i = 0; i < 4; ++i) {
            const int seg = i * 4 + wid;                 // wave-uniform
            const long grow = (long)(seg * 8 + srow);
            __builtin_amdgcn_global_load_lds(
                (const __attribute__((address_space(1))) void*)(gA + grow * K + k0 + scol),
                (__attribute__((address_space(3))) void*)(sA + seg * 512),
                16, 0, 0);
            __builtin_amdgcn_global_load_lds(
                (const __attribute__((address_space(1))) void*)(gB + grow * K + k0 + scol),
                (__attribute__((address_space(3))) void*)(sB + seg * 512),
                16, 0, 0);
        }
        __syncthreads();   // drains vmcnt -> LDS tiles ready

        #pragma unroll
        for (int kk = 0; kk < BK; kk += 32) {
            // logical 16B chunk this lane's quad reads, then XOR-unswizzle.
            // row&7 == lane&7 for all fragment rows (row = base16*16 + (lane&15)).
            const int lc = (kk >> 3) + (lane >> 4);          // logical chunk 0..7
            const int pc = (lc ^ (lane & 7)) * 8;            // physical short offset
            short8 af[4], bfr[4];
            #pragma unroll
            for (int tm = 0; tm < 4; ++tm)
                af[tm] = *(const short8*)(sA + (waveM + tm * 16 + (lane & 15)) * BK + pc);
            #pragma unroll
            for (int tn = 0; tn < 4; ++tn)
                bfr[tn] = *(const short8*)(sB + (waveN + tn * 16 + (lane & 15)) * BK + pc);
            #pragma unroll
            for (int tm = 0; tm < 4; ++tm)
                #pragma unroll
                for (int tn = 0; tn < 4; ++tn)
                    acc[tm][tn] = __builtin_amdgcn_mfma_f32_16x16x32_bf16(
                        af[tm], bfr[tn], acc[tm][tn], 0, 0, 0);
        }

        // ADC quantize at each 128-K chunk boundary (every 2nd BK iter)
        if (((k0 + BK) & 127) == 0) {
            #pragma unroll
            for (int tm = 0; tm < 4; ++tm)
                #pragma unroll
                for (int tn = 0; tn < 4; ++tn) {
                    #pragma unroll
                    for (int r = 0; r < 4; ++r) {
                        float v = acc[tm][tn][r];
                        v = __builtin_amdgcn_fmed3f(v, -255.0f, 255.0f); // clamp
                        v = __builtin_rintf(v);                          // v_rndne
                        macc[tm][tn][r] += v;
                    }
                    acc[tm][tn] = (floatx4){0.f, 0.f, 0.f, 0.f};
                }
        }
        __syncthreads();   // protect LDS before next stage
    }

    const float invs = 2.56f / 255.0f;
    #pragma unroll
    for (int tn = 0; tn < 4; ++tn) {
        const int col = n0 + waveN + tn * 16 + (lane & 15);
        const float bv = bias[col];
        #pragma unroll
        for (int tm = 0; tm < 4; ++tm) {
            const int row = m0 + waveM + tm * 16 + (lane >> 4) * 4;
            #pragma unroll
            for (int r = 0; r < 4; ++r)
                out[(long)(row + r) * N + col] = macc[tm][tn][r] * invs + bv;
        }
    }
}

extern "C" void kernel_launch(void* const* d_in, const int* in_sizes, int n_in,
                              void* d_out, int out_size, void* d_ws, size_t ws_size,
                              hipStream_t stream) {
    const float* x    = (const float*)d_in[0];
    const float* w    = (const float*)d_in[1];
    const float* bias = (const float*)d_in[2];
    // d_in[3] = layer (unused)

    const int N = in_sizes[2];
    const int K = in_sizes[1] / N;
    const int B = in_sizes[0] / K;
    float* out = (float*)d_out;

    // workspace layout: bf16 x [B*K], bf16 w*s [N*K]  (needs ~101 MB)
    unsigned short* xb = (unsigned short*)d_ws;
    unsigned short* wb = xb + (size_t)B * K;

    {
        long n4 = ((long)B * K) / 4;
        cast_x_kernel<<<4096, 256, 0, stream>>>(x, xb, n4);
    }
    {
        long n4 = ((long)N * K) / 4;
        cast_w_kernel<<<4096, 256, 0, stream>>>(w, wb, n4);
    }
    dim3 grid(N / BN, B / BM);
    vmm_kernel<<<grid, 256, 0, stream>>>(xb, wb, bias, out, N, K);
}

// Round 3
// 650.504 us; speedup vs baseline: 2.3308x; 2.3308x over previous
//
#include <hip/hip_runtime.h>

// Chunked VMM with per-128-K-chunk ADC quantization.
//   out[b,n] = sum_{c} q( sum_{k in chunk c} x[b,k]*w[n,k] ) + bias[n]
//   q(p) = round(clip(p,+-2.56) * 255/2.56) * 2.56/255   (round = RTNE)
// Strategy: cast x -> bf16, cast w -> bf16 PRE-SCALED by s=255/2.56 so GEMM
// partials are directly in ADC units; per chunk: med3 clamp, v_rndne, add to
// master accumulator. Final: out = master * (2.56/255) + bias.
// GEMM: 128x128 tile, BK=64, 4 waves x 64x64 (4x4 of mfma_f32_16x16x32_bf16),
// global_load_lds width=16, XOR-swizzled LDS chunks (R2: conflicts 1e8 -> 0).
// R3: launch_bounds back to (256,2) — (256,4) capped VGPRs at 128 and spilled
// the 128-reg accumulator set to scratch (R2: WRITE_SIZE 131MB->3.1GB, 2.4x
// slower). 2 blocks/CU is the structural occupancy for dual accumulators.
// Casts: single shared kernel, 32B loads + 16B packed stores, grid-stride.

typedef __attribute__((ext_vector_type(8))) short short8;            // 8 bf16
typedef __attribute__((ext_vector_type(8))) unsigned short ushort8;  // 16 B store
typedef __attribute__((ext_vector_type(4))) float floatx4;           // MFMA C/D

#define BM 128
#define BN 128
#define BK 64

static __device__ __forceinline__ unsigned short f2bf(float f) {
    union { float f; unsigned int u; } v; v.f = f;
    unsigned int u = v.u;
    unsigned int r = (u + 0x7fffu + ((u >> 16) & 1u)) >> 16;  // RTNE
    return (unsigned short)r;
}

// fp32 -> bf16 with scale; 8 elements/lane/iter: 32B read, 16B write.
__global__ void cast_kernel(const float* __restrict__ in,
                            unsigned short* __restrict__ out,
                            long n8, float s) {
    long i = (long)blockIdx.x * 256 + threadIdx.x;
    const long stride = (long)gridDim.x * 256;
    for (; i < n8; i += stride) {
        float4 a = ((const float4*)in)[2 * i];
        float4 b = ((const float4*)in)[2 * i + 1];
        ushort8 o;
        o[0] = f2bf(a.x * s); o[1] = f2bf(a.y * s);
        o[2] = f2bf(a.z * s); o[3] = f2bf(a.w * s);
        o[4] = f2bf(b.x * s); o[5] = f2bf(b.y * s);
        o[6] = f2bf(b.z * s); o[7] = f2bf(b.w * s);
        ((ushort8*)out)[i] = o;
    }
}

__global__ __launch_bounds__(256, 2) void vmm_kernel(
    const unsigned short* __restrict__ A,   // x   [B,K] bf16
    const unsigned short* __restrict__ Bw,  // w*s [N,K] bf16 (K-contiguous: B^T gemm)
    const float* __restrict__ bias,
    float* __restrict__ out,
    int N, int K)
{
    __shared__ unsigned short sA[BM * BK];
    __shared__ unsigned short sB[BN * BK];

    const int tid  = threadIdx.x;
    const int wid  = tid >> 6;
    const int lane = tid & 63;

    const int m0 = blockIdx.y * BM;
    const int n0 = blockIdx.x * BN;

    const int waveM = (wid >> 1) * 64;
    const int waveN = (wid & 1) * 64;

    floatx4 acc[4][4];   // partial (ADC units), reset every 128 K
    floatx4 macc[4][4];  // master accumulator
    #pragma unroll
    for (int i = 0; i < 4; ++i)
        #pragma unroll
        for (int j = 0; j < 4; ++j) {
            acc[i][j]  = (floatx4){0.f, 0.f, 0.f, 0.f};
            macc[i][j] = (floatx4){0.f, 0.f, 0.f, 0.f};
        }

    // staging: 16 segments of 1 KiB (8 rows x 8 chunks of 16B); 8 lanes/row.
    // XOR swizzle: physical chunk pc holds logical chunk pc ^ (row&7), so the
    // lane at physical (srow, pc) must FETCH global chunk pc ^ srow.
    const int srow = lane >> 3;                        // row within segment 0..7
    const int scol = (((lane & 7) ^ srow) & 7) * 8;    // swizzled bf16 col offset

    const unsigned short* gA = A  + (long)m0 * K;
    const unsigned short* gB = Bw + (long)n0 * K;

    for (int k0 = 0; k0 < K; k0 += BK) {
        #pragma unroll
        for (int i = 0; i < 4; ++i) {
            const int seg = i * 4 + wid;                 // wave-uniform
            const long grow = (long)(seg * 8 + srow);
            __builtin_amdgcn_global_load_lds(
                (const __attribute__((address_space(1))) void*)(gA + grow * K + k0 + scol),
                (__attribute__((address_space(3))) void*)(sA + seg * 512),
                16, 0, 0);
            __builtin_amdgcn_global_load_lds(
                (const __attribute__((address_space(1))) void*)(gB + grow * K + k0 + scol),
                (__attribute__((address_space(3))) void*)(sB + seg * 512),
                16, 0, 0);
        }
        __syncthreads();   // drains vmcnt -> LDS tiles ready

        #pragma unroll
        for (int kk = 0; kk < BK; kk += 32) {
            // logical 16B chunk this lane's quad reads, then XOR-unswizzle.
            // row&7 == lane&7 for all fragment rows (row = base16*16 + (lane&15)).
            const int lc = (kk >> 3) + (lane >> 4);          // logical chunk 0..7
            const int pc = (lc ^ (lane & 7)) * 8;            // physical short offset
            short8 af[4], bfr[4];
            #pragma unroll
            for (int tm = 0; tm < 4; ++tm)
                af[tm] = *(const short8*)(sA + (waveM + tm * 16 + (lane & 15)) * BK + pc);
            #pragma unroll
            for (int tn = 0; tn < 4; ++tn)
                bfr[tn] = *(const short8*)(sB + (waveN + tn * 16 + (lane & 15)) * BK + pc);
            #pragma unroll
            for (int tm = 0; tm < 4; ++tm)
                #pragma unroll
                for (int tn = 0; tn < 4; ++tn)
                    acc[tm][tn] = __builtin_amdgcn_mfma_f32_16x16x32_bf16(
                        af[tm], bfr[tn], acc[tm][tn], 0, 0, 0);
        }

        // ADC quantize at each 128-K chunk boundary (every 2nd BK iter)
        if (((k0 + BK) & 127) == 0) {
            #pragma unroll
            for (int tm = 0; tm < 4; ++tm)
                #pragma unroll
                for (int tn = 0; tn < 4; ++tn) {
                    #pragma unroll
                    for (int r = 0; r < 4; ++r) {
                        float v = acc[tm][tn][r];
                        v = __builtin_amdgcn_fmed3f(v, -255.0f, 255.0f); // clamp
                        v = __builtin_rintf(v);                          // v_rndne
                        macc[tm][tn][r] += v;
                    }
                    acc[tm][tn] = (floatx4){0.f, 0.f, 0.f, 0.f};
                }
        }
        __syncthreads();   // protect LDS before next stage
    }

    const float invs = 2.56f / 255.0f;
    #pragma unroll
    for (int tn = 0; tn < 4; ++tn) {
        const int col = n0 + waveN + tn * 16 + (lane & 15);
        const float bv = bias[col];
        #pragma unroll
        for (int tm = 0; tm < 4; ++tm) {
            const int row = m0 + waveM + tm * 16 + (lane >> 4) * 4;
            #pragma unroll
            for (int r = 0; r < 4; ++r)
                out[(long)(row + r) * N + col] = macc[tm][tn][r] * invs + bv;
        }
    }
}

extern "C" void kernel_launch(void* const* d_in, const int* in_sizes, int n_in,
                              void* d_out, int out_size, void* d_ws, size_t ws_size,
                              hipStream_t stream) {
    const float* x    = (const float*)d_in[0];
    const float* w    = (const float*)d_in[1];
    const float* bias = (const float*)d_in[2];
    // d_in[3] = layer (unused)

    const int N = in_sizes[2];
    const int K = in_sizes[1] / N;
    const int B = in_sizes[0] / K;
    float* out = (float*)d_out;

    // workspace layout: bf16 x [B*K], bf16 w*s [N*K]  (needs ~101 MB)
    unsigned short* xb = (unsigned short*)d_ws;
    unsigned short* wb = xb + (size_t)B * K;

    cast_kernel<<<2048, 256, 0, stream>>>(x, xb, ((long)B * K) / 8, 1.0f);
    cast_kernel<<<2048, 256, 0, stream>>>(w, wb, ((long)N * K) / 8, 99.609375f);

    dim3 grid(N / BN, B / BM);
    vmm_kernel<<<grid, 256, 0, stream>>>(xb, wb, bias, out, N, K);
}